// Round 14
// baseline (718.549 us; speedup 1.0000x reference)
//
#include <hip/hip_runtime.h>
#include <cstddef>

#define BB 64
#define SS 1024
#define NHH 16
#define HDD 2048
#define NE 32
#define NI 1408
#define NT 16
#define SCALE 0.07216878364870322f  // 192^-0.5

typedef float vf4 __attribute__((ext_vector_type(4)));
typedef float vf2 __attribute__((ext_vector_type(2)));

__device__ __forceinline__ vf4 ldnt(const float* p) {
  return __builtin_nontemporal_load((const vf4*)p);
}
__device__ __forceinline__ vf2 ldnt2(const float* p) {
  return __builtin_nontemporal_load((const vf2*)p);
}
__device__ __forceinline__ float ldnt1(const float* p) {
  return __builtin_nontemporal_load(p);
}

// ---------------- RMSNorm (+ transposed copy, + optional CNT zero, + optional fused router) ----------------
__global__ __launch_bounds__(256) void rmsnorm_k(const float* __restrict__ x,
                                                 const float* __restrict__ w,
                                                 float* __restrict__ out,
                                                 float* __restrict__ outT,
                                                 int* __restrict__ cntz,
                                                 const float* __restrict__ wgp,
                                                 float* __restrict__ topw,
                                                 int* __restrict__ counts,
                                                 int* __restrict__ lists) {
  int b = blockIdx.x, tid = threadIdx.x;
  if (cntz && tid == 0 && b < 32) cntz[b] = 0;
  const float* row = x + (size_t)b * HDD;
  float4 v0 = ((const float4*)row)[tid];
  float4 v1 = ((const float4*)row)[tid + 256];
  float ss = v0.x*v0.x + v0.y*v0.y + v0.z*v0.z + v0.w*v0.w
           + v1.x*v1.x + v1.y*v1.y + v1.z*v1.z + v1.w*v1.w;
#pragma unroll
  for (int m = 1; m < 64; m <<= 1) ss += __shfl_xor(ss, m);
  __shared__ float red[4];
  __shared__ float4 wred[4][8];
  int wid = tid >> 6, lane = tid & 63;
  if (lane == 0) red[wid] = ss;
  __syncthreads();
  float tot = red[0] + red[1] + red[2] + red[3];
  float r = rsqrtf(tot * (1.0f / HDD) + 1e-6f);
  float4 w0 = ((const float4*)w)[tid], w1_ = ((const float4*)w)[tid + 256];
  float4 o0, o1;
  o0.x = v0.x*r*w0.x;  o0.y = v0.y*r*w0.y;  o0.z = v0.z*r*w0.z;  o0.w = v0.w*r*w0.w;
  o1.x = v1.x*r*w1_.x; o1.y = v1.y*r*w1_.y; o1.z = v1.z*r*w1_.z; o1.w = v1.w*r*w1_.w;
  ((float4*)(out + (size_t)b * HDD))[tid] = o0;
  ((float4*)(out + (size_t)b * HDD))[tid + 256] = o1;
  int i0 = tid * 4, i1 = 1024 + tid * 4;
  outT[(size_t)(i0 + 0) * BB + b] = o0.x;
  outT[(size_t)(i0 + 1) * BB + b] = o0.y;
  outT[(size_t)(i0 + 2) * BB + b] = o0.z;
  outT[(size_t)(i0 + 3) * BB + b] = o0.w;
  outT[(size_t)(i1 + 0) * BB + b] = o1.x;
  outT[(size_t)(i1 + 1) * BB + b] = o1.y;
  outT[(size_t)(i1 + 2) * BB + b] = o1.z;
  outT[(size_t)(i1 + 3) * BB + b] = o1.w;
  if (!wgp) return;
  // ---- fused router: partial logits (8 h-values x 32 experts) ----
  float hv_[8] = {o0.x, o0.y, o0.z, o0.w, o1.x, o1.y, o1.z, o1.w};
  int hidx[8] = {i0, i0 + 1, i0 + 2, i0 + 3, i1, i1 + 1, i1 + 2, i1 + 3};
  float4 pl[8];
#pragma unroll
  for (int q = 0; q < 8; ++q) { pl[q].x = 0.f; pl[q].y = 0.f; pl[q].z = 0.f; pl[q].w = 0.f; }
#pragma unroll
  for (int t = 0; t < 8; ++t) {
    const float4* wrow = (const float4*)(wgp + (size_t)hidx[t] * NE);
#pragma unroll
    for (int q = 0; q < 8; ++q) {
      float4 wv = wrow[q];
      pl[q].x = fmaf(hv_[t], wv.x, pl[q].x);
      pl[q].y = fmaf(hv_[t], wv.y, pl[q].y);
      pl[q].z = fmaf(hv_[t], wv.z, pl[q].z);
      pl[q].w = fmaf(hv_[t], wv.w, pl[q].w);
    }
  }
#pragma unroll
  for (int m = 1; m < 64; m <<= 1)
#pragma unroll
    for (int q = 0; q < 8; ++q) {
      pl[q].x += __shfl_xor(pl[q].x, m);
      pl[q].y += __shfl_xor(pl[q].y, m);
      pl[q].z += __shfl_xor(pl[q].z, m);
      pl[q].w += __shfl_xor(pl[q].w, m);
    }
  if (lane == 0) {
#pragma unroll
    for (int q = 0; q < 8; ++q) wred[wid][q] = pl[q];
  }
  __syncthreads();
  if (tid == 0) {
    float p[NE];
#pragma unroll
    for (int q = 0; q < 8; ++q) {
      float4 s0 = wred[0][q], s1 = wred[1][q], s2 = wred[2][q], s3 = wred[3][q];
      p[q * 4 + 0] = s0.x + s1.x + s2.x + s3.x;
      p[q * 4 + 1] = s0.y + s1.y + s2.y + s3.y;
      p[q * 4 + 2] = s0.z + s1.z + s2.z + s3.z;
      p[q * 4 + 3] = s0.w + s1.w + s2.w + s3.w;
    }
    float m = -1e30f;
#pragma unroll
    for (int i = 0; i < NE; ++i) m = fmaxf(m, p[i]);
#pragma unroll
    for (int i = 0; i < NE; ++i) p[i] = __expf(p[i] - m);
    unsigned used = 0; float tot2 = 0.f; int sel[4]; float wv[4];
#pragma unroll
    for (int k = 0; k < 4; ++k) {
      float bv = -1.f; int bi = 0;
#pragma unroll
      for (int i = 0; i < NE; ++i) {
        bool c = (!((used >> i) & 1u)) && (p[i] > bv);
        bv = c ? p[i] : bv; bi = c ? i : bi;
      }
      used |= (1u << bi); sel[k] = bi; wv[k] = bv; tot2 += bv;
    }
#pragma unroll
    for (int k = 0; k < 4; ++k) {
      topw[b * 4 + k] = wv[k] / tot2;
      int pos = atomicAdd(&counts[sel[k]], 1);
      lists[sel[k] * BB + pos] = b * 4 + k;
    }
  }
}

// ---------------- combined Q|KV gemv: 6144 cols, CH=64, preloaded weights ----------------
__global__ __launch_bounds__(256) void gemv_qkv(const float* __restrict__ wq,
                                                const float* __restrict__ wkv,
                                                const float* __restrict__ inT,
                                                float* __restrict__ partial) {
  int j = blockIdx.x * 256 + threadIdx.x;  // 0..6143
  const float* W; int col, ldw;
  if (j < 2048) { W = wq;  col = (j >> 7) * 192 + (j & 127); ldw = 3072; }
  else          { W = wkv; col = j - 2048;                   ldw = 4160; }
  int row0 = blockIdx.y * 64;
  float acc[BB];
#pragma unroll
  for (int b = 0; b < BB; ++b) acc[b] = 0.f;
  const float* wp = W + (size_t)row0 * ldw + col;
  const float* hp = inT + (size_t)row0 * BB;
  for (int g = 0; g < 4; ++g) {
    float wr[16];
#pragma unroll
    for (int t = 0; t < 16; ++t) wr[t] = ldnt1(wp + (size_t)(g * 16 + t) * ldw);
#pragma unroll
    for (int t = 0; t < 16; ++t) {
      const float* ht = hp + (g * 16 + t) * BB;
#pragma unroll
      for (int b = 0; b < BB; ++b) acc[b] = fmaf(ht[b], wr[t], acc[b]);
    }
  }
  float* pp = partial + ((size_t)blockIdx.y * BB) * 6144 + j;
#pragma unroll
  for (int b = 0; b < BB; ++b) pp[(size_t)b * 6144] = acc[b];
}

// ---------------- generic skinny GEMV (CH=64, preloaded weights) ----------------
__device__ __forceinline__ void gemv_body(const float* __restrict__ W, int ncols,
                                          const float* __restrict__ inT,
                                          float* __restrict__ partial,
                                          int j, int chunk) {
  int row0 = chunk * 64;
  float acc[BB];
#pragma unroll
  for (int b = 0; b < BB; ++b) acc[b] = 0.f;
  const float* wp = W + (size_t)row0 * ncols + j;
  const float* hp = inT + (size_t)row0 * BB;
  for (int g = 0; g < 4; ++g) {
    float wr[16];
#pragma unroll
    for (int t = 0; t < 16; ++t) wr[t] = ldnt1(wp + (size_t)(g * 16 + t) * ncols);
#pragma unroll
    for (int t = 0; t < 16; ++t) {
      const float* ht = hp + (g * 16 + t) * BB;
#pragma unroll
      for (int b = 0; b < BB; ++b) acc[b] = fmaf(ht[b], wr[t], acc[b]);
    }
  }
  float* pp = partial + ((size_t)chunk * BB) * ncols + j;
#pragma unroll
  for (int b = 0; b < BB; ++b) pp[(size_t)b * ncols] = acc[b];
}

__global__ __launch_bounds__(256) void gemv1(const float* __restrict__ W, int ncols,
                                             const float* __restrict__ inT,
                                             float* __restrict__ partial) {
  gemv_body(W, ncols, inT, partial, blockIdx.x * 256 + threadIdx.x, blockIdx.y);
}

__global__ __launch_bounds__(256) void reduce4_k(const float4* __restrict__ partial, int nchunks,
                                                 int n4, const float4* __restrict__ base,
                                                 float4* __restrict__ out) {
  int i = blockIdx.x * 256 + threadIdx.x;
  if (i >= n4) return;
  float4 s;
  if (base) s = base[i]; else { s.x = s.y = s.z = s.w = 0.f; }
  for (int c = 0; c < nchunks; ++c) {
    float4 p = partial[(size_t)c * n4 + i];
    s.x += p.x; s.y += p.y; s.z += p.z; s.w += p.w;
  }
  out[i] = s;
}

// ---------------- attention: split-K partial blocks ----------------
__global__ __launch_bounds__(256) void attn_part(const float* __restrict__ kc,
                                                 const float* __restrict__ vc,
                                                 const float* __restrict__ qkv,
                                                 const int* __restrict__ slot_map,
                                                 const int* __restrict__ seq_lens,
                                                 float* __restrict__ pacc,
                                                 float* __restrict__ pml) {
  int bh = blockIdx.x, b = bh >> 4, h = bh & 15, j = blockIdx.y;
  int L = seq_lens[b];
  int s0 = j * 256;
  int tid = threadIdx.x, wid = tid >> 6, lane = tid & 63;
  int pidx = bh * 4 + j;
  if (s0 >= L) {
    if (tid == 0) { pml[pidx * 2] = -1e30f; pml[pidx * 2 + 1] = 0.f; }
    return;
  }
  int s1 = min(L, s0 + 256);
  int n = s1 - s0;
  int slot = slot_map[b];
  const float* qkvrow = qkv + (size_t)b * 6144;
  __shared__ float sc[256];
  __shared__ float red[8];
  __shared__ float vred[128];
  // ---- K pass ----
  int sub = lane >> 3;
  int kd = (lane & 7) * 16;
  const float* qrow = qkvrow + h * 128 + kd;
  float4 q0 = ((const float4*)qrow)[0];
  float4 q1 = ((const float4*)qrow)[1];
  float4 q2 = ((const float4*)qrow)[2];
  float4 q3 = ((const float4*)qrow)[3];
  const float* kbase = kc + (((size_t)b * SS) * NHH + h) * 128;
  for (int s = s0 + wid * 8; s < s1; s += 32) {
    int r = s + sub;
    int rc = min(r, s1 - 1);
    const float* kr = kbase + (size_t)rc * 2048 + kd;
    vf4 k0 = ldnt(kr);
    vf4 k1 = ldnt(kr + 4);
    vf4 k2 = ldnt(kr + 8);
    vf4 k3 = ldnt(kr + 12);
    float d = k0.x*q0.x + k0.y*q0.y + k0.z*q0.z + k0.w*q0.w
            + k1.x*q1.x + k1.y*q1.y + k1.z*q1.z + k1.w*q1.w
            + k2.x*q2.x + k2.y*q2.y + k2.z*q2.z + k2.w*q2.w
            + k3.x*q3.x + k3.y*q3.y + k3.z*q3.z + k3.w*q3.w;
    d += __shfl_xor(d, 1); d += __shfl_xor(d, 2); d += __shfl_xor(d, 4);
    if ((lane & 7) == 0 && r < s1) sc[r - s0] = d * SCALE;
  }
  __syncthreads();
  if (slot >= s0 && slot < s1 && wid == 0) {
    const float* kn = qkvrow + 2048 + h * 128;
    float2 k2v = ((const float2*)kn)[lane];
    float2 q2v = ((const float2*)(qkvrow + h * 128))[lane];
    float d = k2v.x * q2v.x + k2v.y * q2v.y;
#pragma unroll
    for (int m = 1; m < 64; m <<= 1) d += __shfl_xor(d, m);
    if (lane == 0) sc[slot - s0] = d * SCALE;
  }
  __syncthreads();
  // ---- local softmax ----
  float v = (tid < n) ? sc[tid] : -1e30f;
  float mx = v;
#pragma unroll
  for (int m = 1; m < 64; m <<= 1) mx = fmaxf(mx, __shfl_xor(mx, m));
  if (lane == 0) red[wid] = mx;
  __syncthreads();
  float M = fmaxf(fmaxf(red[0], red[1]), fmaxf(red[2], red[3]));
  float p = (tid < n) ? __expf(v - M) : 0.f;
  float sm = p;
#pragma unroll
  for (int m = 1; m < 64; m <<= 1) sm += __shfl_xor(sm, m);
  if (lane == 0) red[4 + wid] = sm;
  __syncthreads();
  float l = red[4] + red[5] + red[6] + red[7];
  if (tid < n) sc[tid] = p;
  __syncthreads();
  // ---- V pass, ILP 8 ----
  int d_ = tid & 127, half = tid >> 7;
  const float* vbase = vc + (((size_t)b * SS) * NHH + h) * 128 + d_;
  float a[8];
#pragma unroll
  for (int t = 0; t < 8; ++t) a[t] = 0.f;
  int s = s0 + half;
  for (; s + 14 < s1; s += 16) {
#pragma unroll
    for (int t = 0; t < 8; ++t)
      a[t] = fmaf(sc[s + 2 * t - s0], ldnt1(vbase + (size_t)(s + 2 * t) * 2048), a[t]);
  }
  for (; s < s1; s += 2)
    a[0] = fmaf(sc[s - s0], ldnt1(vbase + (size_t)s * 2048), a[0]);
  float acc = ((a[0] + a[1]) + (a[2] + a[3])) + ((a[4] + a[5]) + (a[6] + a[7]));
  if (slot >= s0 && slot < s1 && half == ((slot ^ s0) & 1)) {
    float vn = qkvrow[4096 + h * 128 + d_];
    float vst = vbase[(size_t)slot * 2048];
    acc += sc[slot - s0] * (vn - vst);
  }
  if (half) vred[d_] = acc;
  __syncthreads();
  if (!half) {
    float tot = acc + vred[d_];
    pacc[(size_t)pidx * 128 + d_] = tot;
    if (d_ == 0) { pml[pidx * 2] = M; pml[pidx * 2 + 1] = l; }
  }
}

__global__ __launch_bounds__(256) void attn_merge(const float* __restrict__ pacc,
                                                  const float* __restrict__ pml,
                                                  float* __restrict__ attnT) {
  int idx = blockIdx.x * 256 + threadIdx.x;  // 131072
  int bh = idx >> 7, d = idx & 127, b = bh >> 4, h = bh & 15;
  float mj[4], lj[4];
  float M = -1e30f;
#pragma unroll
  for (int jj = 0; jj < 4; ++jj) {
    mj[jj] = pml[(bh * 4 + jj) * 2];
    lj[jj] = pml[(bh * 4 + jj) * 2 + 1];
    if (lj[jj] > 0.f) M = fmaxf(M, mj[jj]);
  }
  float denom = 0.f, num = 0.f;
#pragma unroll
  for (int jj = 0; jj < 4; ++jj) {
    if (lj[jj] > 0.f) {
      float e = __expf(mj[jj] - M);
      denom += lj[jj] * e;
      num += pacc[(size_t)(bh * 4 + jj) * 128 + d] * e;
    }
  }
  attnT[((size_t)(h * 128 + d)) * BB + b] = num / denom;
}

// ---------------- fused: moe_up barrier-free (x<176, 2 i's/wave, grouped gathers, SGPR codes) | wse gemv ----------------
__global__ __launch_bounds__(256, 4) void moe_wse(const float* __restrict__ w1,
                                                  const float* __restrict__ h2,
                                                  const int* __restrict__ counts,
                                                  const int* __restrict__ lists,
                                                  const float* __restrict__ topw,
                                                  float* __restrict__ act_buf,
                                                  const float* __restrict__ wse,
                                                  const float* __restrict__ h2T,
                                                  float* __restrict__ partial) {
  int tid = threadIdx.x, wid = tid >> 6, lane = tid & 63;
  if (blockIdx.x >= 176) {
    gemv_body(wse, 2816, h2T, partial, (blockIdx.x - 176) * 256 + tid, blockIdx.y);
    return;
  }
  int e = blockIdx.y;
  int n = counts[e];
  if (n == 0) return;
  int ip = blockIdx.x * 8 + wid * 2;  // 2 i's per wave, 8 per block (176*8=1408)
  const float* gb = w1 + ((size_t)e * 2816 + ip) * HDD;
  const float* ub = w1 + ((size_t)e * 2816 + NI + ip) * HDD;
  for (int c0 = 0; c0 < n; c0 += NT) {
    int codes[NT], hoff[NT];
#pragma unroll
    for (int k = 0; k < NT; ++k) {
      int idx = (c0 + k < n) ? (c0 + k) : c0;
      codes[k] = __builtin_amdgcn_readfirstlane(lists[e * BB + idx]);
      hoff[k] = (codes[k] >> 2) * HDD;
    }
    float ag[2][NT], au[2][NT];
#pragma unroll
    for (int r = 0; r < 2; ++r)
#pragma unroll
      for (int k = 0; k < NT; ++k) { ag[r][k] = 0.f; au[r][k] = 0.f; }
    for (int c = 0; c < 8; ++c) {
      int o = c * 256 + lane * 4;
      vf4 wg4[2], wu4[2];
#pragma unroll
      for (int r = 0; r < 2; ++r) {
        wg4[r] = ldnt(gb + (size_t)r * HDD + o);
        wu4[r] = ldnt(ub + (size_t)r * HDD + o);
      }
#pragma unroll
      for (int kg = 0; kg < 4; ++kg) {
        float4 hv[4];
#pragma unroll
        for (int t = 0; t < 4; ++t)
          hv[t] = *(const float4*)(h2 + (size_t)hoff[kg * 4 + t] + o);
#pragma unroll
        for (int t = 0; t < 4; ++t) {
          int k = kg * 4 + t;
#pragma unroll
          for (int r = 0; r < 2; ++r) {
            ag[r][k] = fmaf(wg4[r].x, hv[t].x, fmaf(wg4[r].y, hv[t].y, fmaf(wg4[r].z, hv[t].z, fmaf(wg4[r].w, hv[t].w, ag[r][k]))));
            au[r][k] = fmaf(wu4[r].x, hv[t].x, fmaf(wu4[r].y, hv[t].y, fmaf(wu4[r].z, hv[t].z, fmaf(wu4[r].w, hv[t].w, au[r][k]))));
          }
        }
        if (kg < 3) __builtin_amdgcn_sched_barrier(0);
      }
    }
#pragma unroll
    for (int m = 1; m < 64; m <<= 1)
#pragma unroll
      for (int r = 0; r < 2; ++r)
#pragma unroll
        for (int k = 0; k < NT; ++k) {
          ag[r][k] += __shfl_xor(ag[r][k], m);
          au[r][k] += __shfl_xor(au[r][k], m);
        }
    float g[2] = {0,0}, u[2] = {0,0}; int code = codes[0];
#pragma unroll
    for (int k = 0; k < NT; ++k) {
      bool sel = (lane == k);
#pragma unroll
      for (int r = 0; r < 2; ++r) { g[r] = sel ? ag[r][k] : g[r]; u[r] = sel ? au[r][k] : u[r]; }
      code = sel ? codes[k] : code;
    }
    int nt = n - c0; if (nt > NT) nt = NT;
    if (lane < nt) {
      float tw = topw[code];
      float2 o;
      o.x = g[0] / (1.f + __expf(-g[0])) * u[0] * tw;
      o.y = g[1] / (1.f + __expf(-g[1])) * u[1] * tw;
      *(float2*)(act_buf + (size_t)code * NI + ip) = o;
    }
  }
}

// ---------------- fused GS reduce + silu*up (transposed out) ----------------
__global__ __launch_bounds__(256) void gs_act_k(const float* __restrict__ partial,
                                                float* __restrict__ act_sT) {
  int i = blockIdx.x * 256 + threadIdx.x;
  if (i >= NI) return;
  int b = blockIdx.y;
  float g = 0.f, u = 0.f;
  for (int c = 0; c < 32; ++c) {
    const float* p = partial + ((size_t)(c * BB + b)) * 2816;
    g += p[i]; u += p[i + NI];
  }
  act_sT[(size_t)i * BB + b] = g / (1.f + __expf(-g)) * u;
}

// ---------------- fused: moe_down barrier-free (x<128, 4 h's/wave, grouped gathers, SGPR codes) | wsd gemv ----------------
__global__ __launch_bounds__(256, 4) void down_wsd(const float* __restrict__ w2,
                                                   const float* __restrict__ act_buf,
                                                   const int* __restrict__ counts,
                                                   const int* __restrict__ lists,
                                                   float* __restrict__ routed,
                                                   const float* __restrict__ wsd,
                                                   const float* __restrict__ actsT,
                                                   float* __restrict__ partial) {
  int tid = threadIdx.x, wid = tid >> 6, lane = tid & 63;
  if (blockIdx.x >= 128) {
    if (blockIdx.y >= 22) return;
    gemv_body(wsd, 2048, actsT, partial, (blockIdx.x - 128) * 256 + tid, blockIdx.y);
    return;
  }
  int e = blockIdx.y;
  int n = counts[e];
  if (n == 0) return;
  int hb = blockIdx.x * 16 + wid * 4;  // 4 h's per wave (128*16=2048)
  const float* rb = w2 + ((size_t)e * HDD + hb) * NI;
  for (int c0 = 0; c0 < n; c0 += NT) {
    int codes[NT], aoff[NT];
#pragma unroll
    for (int k = 0; k < NT; ++k) {
      int idx = (c0 + k < n) ? (c0 + k) : c0;
      codes[k] = __builtin_amdgcn_readfirstlane(lists[e * BB + idx]);
      aoff[k] = codes[k] * NI;
    }
    float ac[4][NT];
#pragma unroll
    for (int r = 0; r < 4; ++r)
#pragma unroll
      for (int k = 0; k < NT; ++k) ac[r][k] = 0.f;
    for (int c = 0; c < 5; ++c) {
      int o = c * 256 + lane * 4;
      vf4 w4[4];
#pragma unroll
      for (int r = 0; r < 4; ++r) w4[r] = ldnt(rb + (size_t)r * NI + o);
#pragma unroll
      for (int kg = 0; kg < 4; ++kg) {
        float4 av[4];
#pragma unroll
        for (int t = 0; t < 4; ++t)
          av[t] = *(const float4*)(act_buf + (size_t)aoff[kg * 4 + t] + o);
#pragma unroll
        for (int t = 0; t < 4; ++t) {
          int k = kg * 4 + t;
#pragma unroll
          for (int r = 0; r < 4; ++r)
            ac[r][k] = fmaf(w4[r].x, av[t].x, fmaf(w4[r].y, av[t].y, fmaf(w4[r].z, av[t].z, fmaf(w4[r].w, av[t].w, ac[r][k]))));
        }
        if (kg < 3) __builtin_amdgcn_sched_barrier(0);
      }
    }
    {
      int o = 1280 + lane * 2;
      vf2 w2v[4];
#pragma unroll
      for (int r = 0; r < 4; ++r) w2v[r] = ldnt2(rb + (size_t)r * NI + o);
#pragma unroll
      for (int kg = 0; kg < 4; ++kg) {
        float2 av[4];
#pragma unroll
        for (int t = 0; t < 4; ++t)
          av[t] = *(const float2*)(act_buf + (size_t)aoff[kg * 4 + t] + o);
#pragma unroll
        for (int t = 0; t < 4; ++t) {
          int k = kg * 4 + t;
#pragma unroll
          for (int r = 0; r < 4; ++r)
            ac[r][k] = fmaf(w2v[r].x, av[t].x, fmaf(w2v[r].y, av[t].y, ac[r][k]));
        }
        if (kg < 3) __builtin_amdgcn_sched_barrier(0);
      }
    }
#pragma unroll
    for (int m = 1; m < 64; m <<= 1)
#pragma unroll
      for (int r = 0; r < 4; ++r)
#pragma unroll
        for (int k = 0; k < NT; ++k) ac[r][k] += __shfl_xor(ac[r][k], m);
    float o[4] = {0,0,0,0}; int code = codes[0];
#pragma unroll
    for (int k = 0; k < NT; ++k) {
      bool sel = (lane == k);
#pragma unroll
      for (int r = 0; r < 4; ++r) o[r] = sel ? ac[r][k] : o[r];
      code = sel ? codes[k] : code;
    }
    int nt = n - c0; if (nt > NT) nt = NT;
    if (lane < nt) {
      float4 o0; o0.x = o[0]; o0.y = o[1]; o0.z = o[2]; o0.w = o[3];
      *(float4*)(routed + (size_t)code * HDD + hb) = o0;
    }
  }
}

// ---------------- final: out = x1 + routed(4) + sum wsd partials ----------------
__global__ __launch_bounds__(256) void final_k(const float4* __restrict__ x1,
                                               const float4* __restrict__ routed,
                                               const float4* __restrict__ partial,
                                               float4* __restrict__ out) {
  int i = blockIdx.x * 256 + threadIdx.x;  // 32768 float4
  int b = i >> 9, c4 = i & 511;
  float4 s = x1[i];
#pragma unroll
  for (int k = 0; k < 4; ++k) {
    float4 r = routed[(size_t)(b * 4 + k) * 512 + c4];
    s.x += r.x; s.y += r.y; s.z += r.z; s.w += r.w;
  }
  for (int c = 0; c < 22; ++c) {
    float4 p = partial[(size_t)c * 32768 + i];
    s.x += p.x; s.y += p.y; s.z += p.z; s.w += p.w;
  }
  out[i] = s;
}

extern "C" void kernel_launch(void* const* d_in, const int* in_sizes, int n_in,
                              void* d_out, int out_size, void* d_ws, size_t ws_size,
                              hipStream_t stream) {
  const float* x     = (const float*)d_in[0];
  const float* kc    = (const float*)d_in[1];
  const float* vc    = (const float*)d_in[2];
  const float* w_ln1 = (const float*)d_in[3];
  const float* w_ln2 = (const float*)d_in[4];
  const float* wq    = (const float*)d_in[5];
  const float* wkv   = (const float*)d_in[6];
  const float* wo    = (const float*)d_in[7];
  const float* wg    = (const float*)d_in[8];
  const float* w1    = (const float*)d_in[9];
  const float* w2    = (const float*)d_in[10];
  const float* wse   = (const float*)d_in[11];
  const float* wsd   = (const float*)d_in[12];
  const int* slot    = (const int*)d_in[13];
  const int* lens    = (const int*)d_in[14];
  float* out = (float*)d_out;
  float* wsf = (float*)d_ws;

  constexpr size_t OFF_H     = 0;
  constexpr size_t OFF_HT    = 131072;
  constexpr size_t OFF_QKV   = 262144;   // 393216
  constexpr size_t OFF_ATTNT = 655360;   // 131072
  constexpr size_t OFF_X1    = 786432;
  constexpr size_t OFF_H2    = 917504;
  constexpr size_t OFF_H2T   = 1048576;
  constexpr size_t OFF_ACTST = 1179648;  // 90112
  constexpr size_t OFF_ACT   = 1269760;  // 360448
  constexpr size_t OFF_ROUT  = 1630208;  // 524288
  constexpr size_t OFF_TOPW  = 2154496;
  constexpr size_t OFF_CNT   = 2154752;
  constexpr size_t OFF_LST   = 2154784;
  constexpr size_t OFF_PACC  = 2156832;  // 524288
  constexpr size_t OFF_PML   = 2681120;  // 8192
  constexpr size_t OFF_PART  = 2689312;  // 12582912

  float* H     = wsf + OFF_H;
  float* HT    = wsf + OFF_HT;
  float* QKV   = wsf + OFF_QKV;
  float* ATTNT = wsf + OFF_ATTNT;
  float* X1    = wsf + OFF_X1;
  float* H2    = wsf + OFF_H2;
  float* H2T   = wsf + OFF_H2T;
  float* ACTST = wsf + OFF_ACTST;
  float* ACT   = wsf + OFF_ACT;
  float* ROUT  = wsf + OFF_ROUT;
  float* TOPW  = wsf + OFF_TOPW;
  int*   CNT   = (int*)(wsf + OFF_CNT);
  int*   LST   = (int*)(wsf + OFF_LST);
  float* PACC  = wsf + OFF_PACC;
  float* PML   = wsf + OFF_PML;
  float* PART  = wsf + OFF_PART;

  rmsnorm_k<<<64, 256, 0, stream>>>(x, w_ln1, H, HT, CNT, nullptr, nullptr, nullptr, nullptr);

  gemv_qkv<<<dim3(24, 32), 256, 0, stream>>>(wq, wkv, HT, PART);
  reduce4_k<<<384, 256, 0, stream>>>((const float4*)PART, 32, 98304, nullptr, (float4*)QKV);

  attn_part<<<dim3(1024, 4), 256, 0, stream>>>(kc, vc, QKV, slot, lens, PACC, PML);
  attn_merge<<<512, 256, 0, stream>>>(PACC, PML, ATTNT);

  gemv1<<<dim3(8, 32), 256, 0, stream>>>(wo, 2048, ATTNT, PART);
  reduce4_k<<<128, 256, 0, stream>>>((const float4*)PART, 32, 32768, (const float4*)x, (float4*)X1);

  rmsnorm_k<<<64, 256, 0, stream>>>(X1, w_ln2, H2, H2T, nullptr, wg, TOPW, CNT, LST);

  moe_wse<<<dim3(187, 32), 256, 0, stream>>>(w1, H2, CNT, LST, TOPW, ACT, wse, H2T, PART);

  gs_act_k<<<dim3(6, 64), 256, 0, stream>>>(PART, ACTST);

  down_wsd<<<dim3(136, 32), 256, 0, stream>>>(w2, ACT, CNT, LST, ROUT, wsd, ACTST, PART);

  final_k<<<128, 256, 0, stream>>>((const float4*)X1, (const float4*)ROUT,
                                   (const float4*)PART, (float4*)out);
}

// Round 15
// 599.886 us; speedup vs baseline: 1.1978x; 1.1978x over previous
//
#include <hip/hip_runtime.h>
#include <cstddef>

#define BB 64
#define SS 1024
#define NHH 16
#define HDD 2048
#define NE 32
#define NI 1408
#define NT 16
#define SCALE 0.07216878364870322f  // 192^-0.5

typedef float vf4 __attribute__((ext_vector_type(4)));
typedef float vf2 __attribute__((ext_vector_type(2)));

__device__ __forceinline__ vf4 ldnt(const float* p) {
  return __builtin_nontemporal_load((const vf4*)p);
}
__device__ __forceinline__ vf2 ldnt2(const float* p) {
  return __builtin_nontemporal_load((const vf2*)p);
}
__device__ __forceinline__ float ldnt1(const float* p) {
  return __builtin_nontemporal_load(p);
}

// ---------------- RMSNorm (+ transposed copy, + optional CNT zero, + optional fused router) ----------------
__global__ __launch_bounds__(256) void rmsnorm_k(const float* __restrict__ x,
                                                 const float* __restrict__ w,
                                                 float* __restrict__ out,
                                                 float* __restrict__ outT,
                                                 int* __restrict__ cntz,
                                                 const float* __restrict__ wgp,
                                                 float* __restrict__ topw,
                                                 int* __restrict__ counts,
                                                 int* __restrict__ lists) {
  int b = blockIdx.x, tid = threadIdx.x;
  if (cntz && tid == 0 && b < 32) cntz[b] = 0;
  const float* row = x + (size_t)b * HDD;
  float4 v0 = ((const float4*)row)[tid];
  float4 v1 = ((const float4*)row)[tid + 256];
  float ss = v0.x*v0.x + v0.y*v0.y + v0.z*v0.z + v0.w*v0.w
           + v1.x*v1.x + v1.y*v1.y + v1.z*v1.z + v1.w*v1.w;
#pragma unroll
  for (int m = 1; m < 64; m <<= 1) ss += __shfl_xor(ss, m);
  __shared__ float red[4];
  __shared__ float4 wred[4][8];
  int wid = tid >> 6, lane = tid & 63;
  if (lane == 0) red[wid] = ss;
  __syncthreads();
  float tot = red[0] + red[1] + red[2] + red[3];
  float r = rsqrtf(tot * (1.0f / HDD) + 1e-6f);
  float4 w0 = ((const float4*)w)[tid], w1_ = ((const float4*)w)[tid + 256];
  float4 o0, o1;
  o0.x = v0.x*r*w0.x;  o0.y = v0.y*r*w0.y;  o0.z = v0.z*r*w0.z;  o0.w = v0.w*r*w0.w;
  o1.x = v1.x*r*w1_.x; o1.y = v1.y*r*w1_.y; o1.z = v1.z*r*w1_.z; o1.w = v1.w*r*w1_.w;
  ((float4*)(out + (size_t)b * HDD))[tid] = o0;
  ((float4*)(out + (size_t)b * HDD))[tid + 256] = o1;
  int i0 = tid * 4, i1 = 1024 + tid * 4;
  outT[(size_t)(i0 + 0) * BB + b] = o0.x;
  outT[(size_t)(i0 + 1) * BB + b] = o0.y;
  outT[(size_t)(i0 + 2) * BB + b] = o0.z;
  outT[(size_t)(i0 + 3) * BB + b] = o0.w;
  outT[(size_t)(i1 + 0) * BB + b] = o1.x;
  outT[(size_t)(i1 + 1) * BB + b] = o1.y;
  outT[(size_t)(i1 + 2) * BB + b] = o1.z;
  outT[(size_t)(i1 + 3) * BB + b] = o1.w;
  if (!wgp) return;
  // ---- fused router: partial logits (8 h-values x 32 experts) ----
  float hv_[8] = {o0.x, o0.y, o0.z, o0.w, o1.x, o1.y, o1.z, o1.w};
  int hidx[8] = {i0, i0 + 1, i0 + 2, i0 + 3, i1, i1 + 1, i1 + 2, i1 + 3};
  float4 pl[8];
#pragma unroll
  for (int q = 0; q < 8; ++q) { pl[q].x = 0.f; pl[q].y = 0.f; pl[q].z = 0.f; pl[q].w = 0.f; }
#pragma unroll
  for (int t = 0; t < 8; ++t) {
    const float4* wrow = (const float4*)(wgp + (size_t)hidx[t] * NE);
#pragma unroll
    for (int q = 0; q < 8; ++q) {
      float4 wv = wrow[q];
      pl[q].x = fmaf(hv_[t], wv.x, pl[q].x);
      pl[q].y = fmaf(hv_[t], wv.y, pl[q].y);
      pl[q].z = fmaf(hv_[t], wv.z, pl[q].z);
      pl[q].w = fmaf(hv_[t], wv.w, pl[q].w);
    }
  }
#pragma unroll
  for (int m = 1; m < 64; m <<= 1)
#pragma unroll
    for (int q = 0; q < 8; ++q) {
      pl[q].x += __shfl_xor(pl[q].x, m);
      pl[q].y += __shfl_xor(pl[q].y, m);
      pl[q].z += __shfl_xor(pl[q].z, m);
      pl[q].w += __shfl_xor(pl[q].w, m);
    }
  if (lane == 0) {
#pragma unroll
    for (int q = 0; q < 8; ++q) wred[wid][q] = pl[q];
  }
  __syncthreads();
  if (tid == 0) {
    float p[NE];
#pragma unroll
    for (int q = 0; q < 8; ++q) {
      float4 s0 = wred[0][q], s1 = wred[1][q], s2 = wred[2][q], s3 = wred[3][q];
      p[q * 4 + 0] = s0.x + s1.x + s2.x + s3.x;
      p[q * 4 + 1] = s0.y + s1.y + s2.y + s3.y;
      p[q * 4 + 2] = s0.z + s1.z + s2.z + s3.z;
      p[q * 4 + 3] = s0.w + s1.w + s2.w + s3.w;
    }
    float m = -1e30f;
#pragma unroll
    for (int i = 0; i < NE; ++i) m = fmaxf(m, p[i]);
#pragma unroll
    for (int i = 0; i < NE; ++i) p[i] = __expf(p[i] - m);
    unsigned used = 0; float tot2 = 0.f; int sel[4]; float wv[4];
#pragma unroll
    for (int k = 0; k < 4; ++k) {
      float bv = -1.f; int bi = 0;
#pragma unroll
      for (int i = 0; i < NE; ++i) {
        bool c = (!((used >> i) & 1u)) && (p[i] > bv);
        bv = c ? p[i] : bv; bi = c ? i : bi;
      }
      used |= (1u << bi); sel[k] = bi; wv[k] = bv; tot2 += bv;
    }
#pragma unroll
    for (int k = 0; k < 4; ++k) {
      topw[b * 4 + k] = wv[k] / tot2;
      int pos = atomicAdd(&counts[sel[k]], 1);
      lists[sel[k] * BB + pos] = b * 4 + k;
    }
  }
}

// ---------------- combined Q|KV gemv: 6144 cols, CH=64, preloaded weights ----------------
__global__ __launch_bounds__(256) void gemv_qkv(const float* __restrict__ wq,
                                                const float* __restrict__ wkv,
                                                const float* __restrict__ inT,
                                                float* __restrict__ partial) {
  int j = blockIdx.x * 256 + threadIdx.x;  // 0..6143
  const float* W; int col, ldw;
  if (j < 2048) { W = wq;  col = (j >> 7) * 192 + (j & 127); ldw = 3072; }
  else          { W = wkv; col = j - 2048;                   ldw = 4160; }
  int row0 = blockIdx.y * 64;
  float acc[BB];
#pragma unroll
  for (int b = 0; b < BB; ++b) acc[b] = 0.f;
  const float* wp = W + (size_t)row0 * ldw + col;
  const float* hp = inT + (size_t)row0 * BB;
  for (int g = 0; g < 4; ++g) {
    float wr[16];
#pragma unroll
    for (int t = 0; t < 16; ++t) wr[t] = ldnt1(wp + (size_t)(g * 16 + t) * ldw);
#pragma unroll
    for (int t = 0; t < 16; ++t) {
      const float* ht = hp + (g * 16 + t) * BB;
#pragma unroll
      for (int b = 0; b < BB; ++b) acc[b] = fmaf(ht[b], wr[t], acc[b]);
    }
  }
  float* pp = partial + ((size_t)blockIdx.y * BB) * 6144 + j;
#pragma unroll
  for (int b = 0; b < BB; ++b) pp[(size_t)b * 6144] = acc[b];
}

// ---------------- generic skinny GEMV (CH=64, preloaded weights) ----------------
__device__ __forceinline__ void gemv_body(const float* __restrict__ W, int ncols,
                                          const float* __restrict__ inT,
                                          float* __restrict__ partial,
                                          int j, int chunk) {
  int row0 = chunk * 64;
  float acc[BB];
#pragma unroll
  for (int b = 0; b < BB; ++b) acc[b] = 0.f;
  const float* wp = W + (size_t)row0 * ncols + j;
  const float* hp = inT + (size_t)row0 * BB;
  for (int g = 0; g < 4; ++g) {
    float wr[16];
#pragma unroll
    for (int t = 0; t < 16; ++t) wr[t] = ldnt1(wp + (size_t)(g * 16 + t) * ncols);
#pragma unroll
    for (int t = 0; t < 16; ++t) {
      const float* ht = hp + (g * 16 + t) * BB;
#pragma unroll
      for (int b = 0; b < BB; ++b) acc[b] = fmaf(ht[b], wr[t], acc[b]);
    }
  }
  float* pp = partial + ((size_t)chunk * BB) * ncols + j;
#pragma unroll
  for (int b = 0; b < BB; ++b) pp[(size_t)b * ncols] = acc[b];
}

__global__ __launch_bounds__(256) void gemv1(const float* __restrict__ W, int ncols,
                                             const float* __restrict__ inT,
                                             float* __restrict__ partial) {
  gemv_body(W, ncols, inT, partial, blockIdx.x * 256 + threadIdx.x, blockIdx.y);
}

__global__ __launch_bounds__(256) void reduce4_k(const float4* __restrict__ partial, int nchunks,
                                                 int n4, const float4* __restrict__ base,
                                                 float4* __restrict__ out) {
  int i = blockIdx.x * 256 + threadIdx.x;
  if (i >= n4) return;
  float4 s;
  if (base) s = base[i]; else { s.x = s.y = s.z = s.w = 0.f; }
  for (int c = 0; c < nchunks; ++c) {
    float4 p = partial[(size_t)c * n4 + i];
    s.x += p.x; s.y += p.y; s.z += p.z; s.w += p.w;
  }
  out[i] = s;
}

// ---------------- attention: split-K partial blocks ----------------
__global__ __launch_bounds__(256) void attn_part(const float* __restrict__ kc,
                                                 const float* __restrict__ vc,
                                                 const float* __restrict__ qkv,
                                                 const int* __restrict__ slot_map,
                                                 const int* __restrict__ seq_lens,
                                                 float* __restrict__ pacc,
                                                 float* __restrict__ pml) {
  int bh = blockIdx.x, b = bh >> 4, h = bh & 15, j = blockIdx.y;
  int L = seq_lens[b];
  int s0 = j * 256;
  int tid = threadIdx.x, wid = tid >> 6, lane = tid & 63;
  int pidx = bh * 4 + j;
  if (s0 >= L) {
    if (tid == 0) { pml[pidx * 2] = -1e30f; pml[pidx * 2 + 1] = 0.f; }
    return;
  }
  int s1 = min(L, s0 + 256);
  int n = s1 - s0;
  int slot = slot_map[b];
  const float* qkvrow = qkv + (size_t)b * 6144;
  __shared__ float sc[256];
  __shared__ float red[8];
  __shared__ float vred[128];
  // ---- K pass ----
  int sub = lane >> 3;
  int kd = (lane & 7) * 16;
  const float* qrow = qkvrow + h * 128 + kd;
  float4 q0 = ((const float4*)qrow)[0];
  float4 q1 = ((const float4*)qrow)[1];
  float4 q2 = ((const float4*)qrow)[2];
  float4 q3 = ((const float4*)qrow)[3];
  const float* kbase = kc + (((size_t)b * SS) * NHH + h) * 128;
  for (int s = s0 + wid * 8; s < s1; s += 32) {
    int r = s + sub;
    int rc = min(r, s1 - 1);
    const float* kr = kbase + (size_t)rc * 2048 + kd;
    vf4 k0 = ldnt(kr);
    vf4 k1 = ldnt(kr + 4);
    vf4 k2 = ldnt(kr + 8);
    vf4 k3 = ldnt(kr + 12);
    float d = k0.x*q0.x + k0.y*q0.y + k0.z*q0.z + k0.w*q0.w
            + k1.x*q1.x + k1.y*q1.y + k1.z*q1.z + k1.w*q1.w
            + k2.x*q2.x + k2.y*q2.y + k2.z*q2.z + k2.w*q2.w
            + k3.x*q3.x + k3.y*q3.y + k3.z*q3.z + k3.w*q3.w;
    d += __shfl_xor(d, 1); d += __shfl_xor(d, 2); d += __shfl_xor(d, 4);
    if ((lane & 7) == 0 && r < s1) sc[r - s0] = d * SCALE;
  }
  __syncthreads();
  if (slot >= s0 && slot < s1 && wid == 0) {
    const float* kn = qkvrow + 2048 + h * 128;
    float2 k2v = ((const float2*)kn)[lane];
    float2 q2v = ((const float2*)(qkvrow + h * 128))[lane];
    float d = k2v.x * q2v.x + k2v.y * q2v.y;
#pragma unroll
    for (int m = 1; m < 64; m <<= 1) d += __shfl_xor(d, m);
    if (lane == 0) sc[slot - s0] = d * SCALE;
  }
  __syncthreads();
  // ---- local softmax ----
  float v = (tid < n) ? sc[tid] : -1e30f;
  float mx = v;
#pragma unroll
  for (int m = 1; m < 64; m <<= 1) mx = fmaxf(mx, __shfl_xor(mx, m));
  if (lane == 0) red[wid] = mx;
  __syncthreads();
  float M = fmaxf(fmaxf(red[0], red[1]), fmaxf(red[2], red[3]));
  float p = (tid < n) ? __expf(v - M) : 0.f;
  float sm = p;
#pragma unroll
  for (int m = 1; m < 64; m <<= 1) sm += __shfl_xor(sm, m);
  if (lane == 0) red[4 + wid] = sm;
  __syncthreads();
  float l = red[4] + red[5] + red[6] + red[7];
  if (tid < n) sc[tid] = p;
  __syncthreads();
  // ---- V pass, ILP 8 ----
  int d_ = tid & 127, half = tid >> 7;
  const float* vbase = vc + (((size_t)b * SS) * NHH + h) * 128 + d_;
  float a[8];
#pragma unroll
  for (int t = 0; t < 8; ++t) a[t] = 0.f;
  int s = s0 + half;
  for (; s + 14 < s1; s += 16) {
#pragma unroll
    for (int t = 0; t < 8; ++t)
      a[t] = fmaf(sc[s + 2 * t - s0], ldnt1(vbase + (size_t)(s + 2 * t) * 2048), a[t]);
  }
  for (; s < s1; s += 2)
    a[0] = fmaf(sc[s - s0], ldnt1(vbase + (size_t)s * 2048), a[0]);
  float acc = ((a[0] + a[1]) + (a[2] + a[3])) + ((a[4] + a[5]) + (a[6] + a[7]));
  if (slot >= s0 && slot < s1 && half == ((slot ^ s0) & 1)) {
    float vn = qkvrow[4096 + h * 128 + d_];
    float vst = vbase[(size_t)slot * 2048];
    acc += sc[slot - s0] * (vn - vst);
  }
  if (half) vred[d_] = acc;
  __syncthreads();
  if (!half) {
    float tot = acc + vred[d_];
    pacc[(size_t)pidx * 128 + d_] = tot;
    if (d_ == 0) { pml[pidx * 2] = M; pml[pidx * 2 + 1] = l; }
  }
}

__global__ __launch_bounds__(256) void attn_merge(const float* __restrict__ pacc,
                                                  const float* __restrict__ pml,
                                                  float* __restrict__ attnT) {
  int idx = blockIdx.x * 256 + threadIdx.x;  // 131072
  int bh = idx >> 7, d = idx & 127, b = bh >> 4, h = bh & 15;
  float mj[4], lj[4];
  float M = -1e30f;
#pragma unroll
  for (int jj = 0; jj < 4; ++jj) {
    mj[jj] = pml[(bh * 4 + jj) * 2];
    lj[jj] = pml[(bh * 4 + jj) * 2 + 1];
    if (lj[jj] > 0.f) M = fmaxf(M, mj[jj]);
  }
  float denom = 0.f, num = 0.f;
#pragma unroll
  for (int jj = 0; jj < 4; ++jj) {
    if (lj[jj] > 0.f) {
      float e = __expf(mj[jj] - M);
      denom += lj[jj] * e;
      num += pacc[(size_t)(bh * 4 + jj) * 128 + d] * e;
    }
  }
  attnT[((size_t)(h * 128 + d)) * BB + b] = num / denom;
}

// ---------------- fused: moe_up barrier-free (x<176, 2 i's/wave, grouped gathers) | wse gemv ----------------
__global__ __launch_bounds__(256, 3) void moe_wse(const float* __restrict__ w1,
                                                  const float* __restrict__ h2,
                                                  const int* __restrict__ counts,
                                                  const int* __restrict__ lists,
                                                  const float* __restrict__ topw,
                                                  float* __restrict__ act_buf,
                                                  const float* __restrict__ wse,
                                                  const float* __restrict__ h2T,
                                                  float* __restrict__ partial) {
  int tid = threadIdx.x, wid = tid >> 6, lane = tid & 63;
  if (blockIdx.x >= 176) {
    gemv_body(wse, 2816, h2T, partial, (blockIdx.x - 176) * 256 + tid, blockIdx.y);
    return;
  }
  int e = blockIdx.y;
  int n = counts[e];
  if (n == 0) return;
  int ip = blockIdx.x * 8 + wid * 2;  // 2 i's per wave, 8 per block (176*8=1408)
  const float* gb = w1 + ((size_t)e * 2816 + ip) * HDD;
  const float* ub = w1 + ((size_t)e * 2816 + NI + ip) * HDD;
  for (int c0 = 0; c0 < n; c0 += NT) {
    int codes[NT], hoff[NT];
#pragma unroll
    for (int k = 0; k < NT; ++k) {
      int idx = (c0 + k < n) ? (c0 + k) : c0;
      codes[k] = lists[e * BB + idx];
      hoff[k] = (codes[k] >> 2) * HDD;
    }
    float ag[2][NT], au[2][NT];
#pragma unroll
    for (int r = 0; r < 2; ++r)
#pragma unroll
      for (int k = 0; k < NT; ++k) { ag[r][k] = 0.f; au[r][k] = 0.f; }
    for (int c = 0; c < 8; ++c) {
      int o = c * 256 + lane * 4;
      vf4 wg4[2], wu4[2];
#pragma unroll
      for (int r = 0; r < 2; ++r) {
        wg4[r] = ldnt(gb + (size_t)r * HDD + o);
        wu4[r] = ldnt(ub + (size_t)r * HDD + o);
      }
#pragma unroll
      for (int kg = 0; kg < 4; ++kg) {
        float4 hv[4];
#pragma unroll
        for (int t = 0; t < 4; ++t)
          hv[t] = *(const float4*)(h2 + (size_t)hoff[kg * 4 + t] + o);
#pragma unroll
        for (int t = 0; t < 4; ++t) {
          int k = kg * 4 + t;
#pragma unroll
          for (int r = 0; r < 2; ++r) {
            ag[r][k] = fmaf(wg4[r].x, hv[t].x, fmaf(wg4[r].y, hv[t].y, fmaf(wg4[r].z, hv[t].z, fmaf(wg4[r].w, hv[t].w, ag[r][k]))));
            au[r][k] = fmaf(wu4[r].x, hv[t].x, fmaf(wu4[r].y, hv[t].y, fmaf(wu4[r].z, hv[t].z, fmaf(wu4[r].w, hv[t].w, au[r][k]))));
          }
        }
        if (kg < 3) __builtin_amdgcn_sched_barrier(0);
      }
    }
#pragma unroll
    for (int m = 1; m < 64; m <<= 1)
#pragma unroll
      for (int r = 0; r < 2; ++r)
#pragma unroll
        for (int k = 0; k < NT; ++k) {
          ag[r][k] += __shfl_xor(ag[r][k], m);
          au[r][k] += __shfl_xor(au[r][k], m);
        }
    float g[2] = {0,0}, u[2] = {0,0}; int code = codes[0];
#pragma unroll
    for (int k = 0; k < NT; ++k) {
      bool sel = (lane == k);
#pragma unroll
      for (int r = 0; r < 2; ++r) { g[r] = sel ? ag[r][k] : g[r]; u[r] = sel ? au[r][k] : u[r]; }
      code = sel ? codes[k] : code;
    }
    int nt = n - c0; if (nt > NT) nt = NT;
    if (lane < nt) {
      float tw = topw[code];
      float2 o;
      o.x = g[0] / (1.f + __expf(-g[0])) * u[0] * tw;
      o.y = g[1] / (1.f + __expf(-g[1])) * u[1] * tw;
      *(float2*)(act_buf + (size_t)code * NI + ip) = o;
    }
  }
}

// ---------------- fused GS reduce + silu*up (transposed out) ----------------
__global__ __launch_bounds__(256) void gs_act_k(const float* __restrict__ partial,
                                                float* __restrict__ act_sT) {
  int i = blockIdx.x * 256 + threadIdx.x;
  if (i >= NI) return;
  int b = blockIdx.y;
  float g = 0.f, u = 0.f;
  for (int c = 0; c < 32; ++c) {
    const float* p = partial + ((size_t)(c * BB + b)) * 2816;
    g += p[i]; u += p[i + NI];
  }
  act_sT[(size_t)i * BB + b] = g / (1.f + __expf(-g)) * u;
}

// ---------------- fused: moe_down barrier-free (x<128, 4 h's/wave, grouped gathers) | wsd gemv ----------------
__global__ __launch_bounds__(256, 3) void down_wsd(const float* __restrict__ w2,
                                                   const float* __restrict__ act_buf,
                                                   const int* __restrict__ counts,
                                                   const int* __restrict__ lists,
                                                   float* __restrict__ routed,
                                                   const float* __restrict__ wsd,
                                                   const float* __restrict__ actsT,
                                                   float* __restrict__ partial) {
  int tid = threadIdx.x, wid = tid >> 6, lane = tid & 63;
  if (blockIdx.x >= 128) {
    if (blockIdx.y >= 22) return;
    gemv_body(wsd, 2048, actsT, partial, (blockIdx.x - 128) * 256 + tid, blockIdx.y);
    return;
  }
  int e = blockIdx.y;
  int n = counts[e];
  if (n == 0) return;
  int hb = blockIdx.x * 16 + wid * 4;  // 4 h's per wave (128*16=2048)
  const float* rb = w2 + ((size_t)e * HDD + hb) * NI;
  for (int c0 = 0; c0 < n; c0 += NT) {
    int codes[NT], aoff[NT];
#pragma unroll
    for (int k = 0; k < NT; ++k) {
      int idx = (c0 + k < n) ? (c0 + k) : c0;
      codes[k] = lists[e * BB + idx];
      aoff[k] = codes[k] * NI;
    }
    float ac[4][NT];
#pragma unroll
    for (int r = 0; r < 4; ++r)
#pragma unroll
      for (int k = 0; k < NT; ++k) ac[r][k] = 0.f;
    for (int c = 0; c < 5; ++c) {
      int o = c * 256 + lane * 4;
      vf4 w4[4];
#pragma unroll
      for (int r = 0; r < 4; ++r) w4[r] = ldnt(rb + (size_t)r * NI + o);
#pragma unroll
      for (int kg = 0; kg < 4; ++kg) {
        float4 av[4];
#pragma unroll
        for (int t = 0; t < 4; ++t)
          av[t] = *(const float4*)(act_buf + (size_t)aoff[kg * 4 + t] + o);
#pragma unroll
        for (int t = 0; t < 4; ++t) {
          int k = kg * 4 + t;
#pragma unroll
          for (int r = 0; r < 4; ++r)
            ac[r][k] = fmaf(w4[r].x, av[t].x, fmaf(w4[r].y, av[t].y, fmaf(w4[r].z, av[t].z, fmaf(w4[r].w, av[t].w, ac[r][k]))));
        }
        if (kg < 3) __builtin_amdgcn_sched_barrier(0);
      }
    }
    {
      int o = 1280 + lane * 2;
      vf2 w2v[4];
#pragma unroll
      for (int r = 0; r < 4; ++r) w2v[r] = ldnt2(rb + (size_t)r * NI + o);
#pragma unroll
      for (int kg = 0; kg < 4; ++kg) {
        float2 av[4];
#pragma unroll
        for (int t = 0; t < 4; ++t)
          av[t] = *(const float2*)(act_buf + (size_t)aoff[kg * 4 + t] + o);
#pragma unroll
        for (int t = 0; t < 4; ++t) {
          int k = kg * 4 + t;
#pragma unroll
          for (int r = 0; r < 4; ++r)
            ac[r][k] = fmaf(w2v[r].x, av[t].x, fmaf(w2v[r].y, av[t].y, ac[r][k]));
        }
        if (kg < 3) __builtin_amdgcn_sched_barrier(0);
      }
    }
#pragma unroll
    for (int m = 1; m < 64; m <<= 1)
#pragma unroll
      for (int r = 0; r < 4; ++r)
#pragma unroll
        for (int k = 0; k < NT; ++k) ac[r][k] += __shfl_xor(ac[r][k], m);
    float o[4] = {0,0,0,0}; int code = codes[0];
#pragma unroll
    for (int k = 0; k < NT; ++k) {
      bool sel = (lane == k);
#pragma unroll
      for (int r = 0; r < 4; ++r) o[r] = sel ? ac[r][k] : o[r];
      code = sel ? codes[k] : code;
    }
    int nt = n - c0; if (nt > NT) nt = NT;
    if (lane < nt) {
      float4 o0; o0.x = o[0]; o0.y = o[1]; o0.z = o[2]; o0.w = o[3];
      *(float4*)(routed + (size_t)code * HDD + hb) = o0;
    }
  }
}

// ---------------- final: out = x1 + routed(4) + sum wsd partials ----------------
__global__ __launch_bounds__(256) void final_k(const float4* __restrict__ x1,
                                               const float4* __restrict__ routed,
                                               const float4* __restrict__ partial,
                                               float4* __restrict__ out) {
  int i = blockIdx.x * 256 + threadIdx.x;  // 32768 float4
  int b = i >> 9, c4 = i & 511;
  float4 s = x1[i];
#pragma unroll
  for (int k = 0; k < 4; ++k) {
    float4 r = routed[(size_t)(b * 4 + k) * 512 + c4];
    s.x += r.x; s.y += r.y; s.z += r.z; s.w += r.w;
  }
  for (int c = 0; c < 22; ++c) {
    float4 p = partial[(size_t)c * 32768 + i];
    s.x += p.x; s.y += p.y; s.z += p.z; s.w += p.w;
  }
  out[i] = s;
}

extern "C" void kernel_launch(void* const* d_in, const int* in_sizes, int n_in,
                              void* d_out, int out_size, void* d_ws, size_t ws_size,
                              hipStream_t stream) {
  const float* x     = (const float*)d_in[0];
  const float* kc    = (const float*)d_in[1];
  const float* vc    = (const float*)d_in[2];
  const float* w_ln1 = (const float*)d_in[3];
  const float* w_ln2 = (const float*)d_in[4];
  const float* wq    = (const float*)d_in[5];
  const float* wkv   = (const float*)d_in[6];
  const float* wo    = (const float*)d_in[7];
  const float* wg    = (const float*)d_in[8];
  const float* w1    = (const float*)d_in[9];
  const float* w2    = (const float*)d_in[10];
  const float* wse   = (const float*)d_in[11];
  const float* wsd   = (const float*)d_in[12];
  const int* slot    = (const int*)d_in[13];
  const int* lens    = (const int*)d_in[14];
  float* out = (float*)d_out;
  float* wsf = (float*)d_ws;

  constexpr size_t OFF_H     = 0;
  constexpr size_t OFF_HT    = 131072;
  constexpr size_t OFF_QKV   = 262144;   // 393216
  constexpr size_t OFF_ATTNT = 655360;   // 131072
  constexpr size_t OFF_X1    = 786432;
  constexpr size_t OFF_H2    = 917504;
  constexpr size_t OFF_H2T   = 1048576;
  constexpr size_t OFF_ACTST = 1179648;  // 90112
  constexpr size_t OFF_ACT   = 1269760;  // 360448
  constexpr size_t OFF_ROUT  = 1630208;  // 524288
  constexpr size_t OFF_TOPW  = 2154496;
  constexpr size_t OFF_CNT   = 2154752;
  constexpr size_t OFF_LST   = 2154784;
  constexpr size_t OFF_PACC  = 2156832;  // 524288
  constexpr size_t OFF_PML   = 2681120;  // 8192
  constexpr size_t OFF_PART  = 2689312;  // 12582912

  float* H     = wsf + OFF_H;
  float* HT    = wsf + OFF_HT;
  float* QKV   = wsf + OFF_QKV;
  float* ATTNT = wsf + OFF_ATTNT;
  float* X1    = wsf + OFF_X1;
  float* H2    = wsf + OFF_H2;
  float* H2T   = wsf + OFF_H2T;
  float* ACTST = wsf + OFF_ACTST;
  float* ACT   = wsf + OFF_ACT;
  float* ROUT  = wsf + OFF_ROUT;
  float* TOPW  = wsf + OFF_TOPW;
  int*   CNT   = (int*)(wsf + OFF_CNT);
  int*   LST   = (int*)(wsf + OFF_LST);
  float* PACC  = wsf + OFF_PACC;
  float* PML   = wsf + OFF_PML;
  float* PART  = wsf + OFF_PART;

  rmsnorm_k<<<64, 256, 0, stream>>>(x, w_ln1, H, HT, CNT, nullptr, nullptr, nullptr, nullptr);

  gemv_qkv<<<dim3(24, 32), 256, 0, stream>>>(wq, wkv, HT, PART);
  reduce4_k<<<384, 256, 0, stream>>>((const float4*)PART, 32, 98304, nullptr, (float4*)QKV);

  attn_part<<<dim3(1024, 4), 256, 0, stream>>>(kc, vc, QKV, slot, lens, PACC, PML);
  attn_merge<<<512, 256, 0, stream>>>(PACC, PML, ATTNT);

  gemv1<<<dim3(8, 32), 256, 0, stream>>>(wo, 2048, ATTNT, PART);
  reduce4_k<<<128, 256, 0, stream>>>((const float4*)PART, 32, 32768, (const float4*)x, (float4*)X1);

  rmsnorm_k<<<64, 256, 0, stream>>>(X1, w_ln2, H2, H2T, nullptr, wg, TOPW, CNT, LST);

  moe_wse<<<dim3(187, 32), 256, 0, stream>>>(w1, H2, CNT, LST, TOPW, ACT, wse, H2T, PART);

  gs_act_k<<<dim3(6, 64), 256, 0, stream>>>(PART, ACTST);

  down_wsd<<<dim3(136, 32), 256, 0, stream>>>(w2, ACT, CNT, LST, ROUT, wsd, ACTST, PART);

  final_k<<<128, 256, 0, stream>>>((const float4*)X1, (const float4*)ROUT,
                                   (const float4*)PART, (float4*)out);
}